// Round 1
// baseline (269.622 us; speedup 1.0000x reference)
//
#include <hip/hip_runtime.h>
#include <hip/hip_bf16.h>

using bf16 = __hip_bfloat16;
typedef __attribute__((ext_vector_type(8))) short short8x;            // 8 bf16 (4 VGPRs)
typedef __attribute__((ext_vector_type(4))) short short4x;            // 4 bf16
typedef __attribute__((ext_vector_type(4))) unsigned short ushort4x;  // 4 bf16 bits
typedef __attribute__((ext_vector_type(4))) float f32x4;              // MFMA accumulator

__device__ __forceinline__ float b2f(bf16 x) { return __bfloat162float(x); }
__device__ __forceinline__ bf16  f2b(float x) { return __float2bfloat16(x); }
__device__ __forceinline__ short bbits(float x) { bf16 b = f2b(x); short s; __builtin_memcpy(&s, &b, 2); return s; }
__device__ __forceinline__ float bu2f(unsigned short s) {
    unsigned v = ((unsigned)s) << 16; float f; __builtin_memcpy(&f, &v, 4); return f;
}
// flag-dispatched input load: f32==1 -> fp32 storage, else bf16 storage
__device__ __forceinline__ float ldin(const void* p, int i, int f32) {
    return f32 ? ((const float*)p)[i] : b2f(((const bf16*)p)[i]);
}

// branchless erf-based gelu (A&S 7.1.26, |eps_erf| <= 1.5e-7) — replaces libm erff
__device__ __forceinline__ float gelu_f(float x) {
    const float u = x * 0.70710678118654752f;
    const float z = fabsf(u);
    const float t = __builtin_amdgcn_rcpf(fmaf(0.3275911f, z, 1.0f));
    float pl = fmaf(1.061405429f, t, -1.453152027f);
    pl = fmaf(pl, t, 1.421413741f);
    pl = fmaf(pl, t, -0.284496736f);
    pl = fmaf(pl, t, 0.254829592f);
    pl *= t;
    const float e = __builtin_amdgcn_exp2f((z * z) * -1.4426950408889634f);
    float er = fmaf(-pl, e, 1.0f);          // erf(|u|)
    er = __builtin_copysignf(er, u);        // erf(u)
    const float g = 0.5f * x;
    return fmaf(g, er, g);                  // 0.5*x*(1+erf)
}

// problem dims (fixed by setup_inputs)
#define TI 6
#define HI 40
#define WI 40
#define TO 12
#define HO 80
#define WO 80
#define NIN (TI*HI*WI)    // 9600
#define NOUT (TO*HO*WO)   // 76800

// ---------------- workspace layout ----------------
// [0, Q_BYTES)            : Q bf16 [8][NIN][256]  (corner projections through fc1: Q=feat·Wq^T)
// [+WQP_BYTES)            : WqP bf16 [8 k][2 kc][16 nt][64 lane][8]  (Wq B-fragments)
// float region F (offsets in floats):
#define F_B1    0                       // [256] effective pw1 bias (o-space)
#define F_ACO   (F_B1 + 256)            // [6][256] rel-coord coefficients (o-space)
#define F_SCW   (F_ACO + 6*256)         // [3][64] sc_pw_w*sc_dw_w
#define F_SCB   (F_SCW + 3*64)          // [3] folded sc bias (pad 4)
#define F_SC    (F_SCB + 4)             // [3][NIN] shortcut conv output
#define F_DT    (F_SC + 3*NIN)          // [2][TO] signed d (t axis)
#define F_DH    (F_DT + 2*TO)           // [2][HO]
#define F_DW    (F_DH + 2*HO)           // [2][WO]
#define F_FT    (F_DW + 2*WO)           // [TO] trilinear frac
#define F_FH    (F_FT + TO)             // [HO]
#define F_FW    (F_FH + HO)             // [WO]
#define F_FC2W  (F_FW + WO)             // [3*256] fc2 weights (fp32 staged)
#define F_FC2B  (F_FC2W + 768)          // [3] fc2 bias (pad 4)
#define F_B2    (F_FC2B + 4)            // [256] fc1-folded bias: fc1_b + fc1_w·b1eff
#define F_A2    (F_B2 + 256)            // [6][256] fc1-folded coord coeffs: fc1_w·A
#define F_END   (F_A2 + 6*256)
// int region I (offsets in ints), starts right after F region:
#define I_IT    0                       // [2][TO] nearest idx
#define I_IH    (I_IT + 2*TO)           // [2][HO]
#define I_IW    (I_IH + 2*HO)           // [2][WO]
#define I_LT0   (I_IW + 2*WO)           // [TO] trilinear i0
#define I_LT1   (I_LT0 + TO)
#define I_LH0   (I_LT1 + TO)
#define I_LH1   (I_LH0 + HO)
#define I_LW0   (I_LH1 + HO)
#define I_LW1   (I_LW0 + WO)
#define I_FLAG  (I_LW1 + WO)            // [1] 1 = fp32 storage, 0 = bf16 storage
#define I_END   (I_FLAG + 1)

#define MPOS 32     // positions per k_main block
#define ZPAD 264    // bf16 row stride for zt LDS tile in k_corner
#define FT_S 72     // bf16 row stride for feat tile in k_corner (16B-aligned rows)

// per-axis tables, replicating reference `near` (eps=1e-6, round-half-even) and `lin_idx`
__device__ __forceinline__ void axis_tables(int i, int n_out, int n_in,
                                            float* dvals, int* ivals,
                                            int* l0, int* l1, float* fr) {
    const float r_out = 1.0f / (float)n_out;
    const float r_in  = 1.0f / (float)n_in;
    const float c = -1.0f + r_out + 2.0f * r_out * (float)i;
    #pragma unroll
    for (int v = 0; v < 2; ++v) {
        const float vv = v ? 1.0f : -1.0f;
        float cc = c + vv * r_in + 1e-6f;
        cc = fminf(fmaxf(cc, -1.0f + 1e-6f), 1.0f - 1e-6f);
        float fx = rintf(((cc + 1.0f) * (float)n_in - 1.0f) * 0.5f);
        fx = fminf(fmaxf(fx, 0.0f), (float)(n_in - 1));
        const int idx = (int)fx;
        const float l = -1.0f + r_in + 2.0f * r_in * (float)idx;
        dvals[v * n_out + i] = (c - l) * (float)n_in;
        ivals[v * n_out + i] = idx;
    }
    float x = fminf(fmaxf(((c + 1.0f) * (float)n_in - 1.0f) * 0.5f, 0.0f), (float)(n_in - 1));
    const float x0 = floorf(x);
    fr[i] = x - x0;
    const int i0 = (int)x0;
    l0[i] = i0;
    l1[i] = min(i0 + 1, n_in - 1);
}

// ---------------- kernel A: merged setup (320 blocks) ----------------
// blocks 0..255 : B1/ACO fold per output channel o (block 0 also: tables + small folds)
// blocks 256..319: pack Wq[k][j][c] = sum_o fc1_w[j][o]*pw1_w[o][ch]*dw1_w[ch] -> B-fragments
__global__ __launch_bounds__(256)
void k_setup(const void* __restrict__ feat,
             const void* __restrict__ dw1_w, const void* __restrict__ dw1_b,
             const void* __restrict__ pw1_w, const void* __restrict__ pw1_b,
             const void* __restrict__ fc1_w, const void* __restrict__ fc1_b,
             const void* __restrict__ fc2_w, const void* __restrict__ fc2_b,
             const void* __restrict__ sc_dw_w, const void* __restrict__ sc_dw_b,
             const void* __restrict__ sc_pw_w, const void* __restrict__ sc_pw_b,
             bf16* __restrict__ WqP, float* __restrict__ F, int* __restrict__ I) {
    const int tid = threadIdx.x;
    const int b = blockIdx.x;
    __shared__ int sflag;
    // per-block dtype detection (wave-0 ballot): even halfwords of fp32 data
    // are mantissa junk (~15% in bf16-exponent window); of bf16 data ~100%.
    if (tid < 64) {
        const unsigned short* u = (const unsigned short*)feat;
        const unsigned e = (u[2 * tid] >> 7) & 0xFFu;
        const unsigned long long m = __ballot(e >= 0x68u && e <= 0x8Eu);
        if (tid == 0) sflag = (__popcll(m) < 32) ? 1 : 0;
    }
    __syncthreads();
    const int f32 = sflag;

    if (b >= 256) {           // ---- WqP pack duty (fc1 folded into corner weights) ----
        const int g = (b - 256) * 256 + tid;     // 0..16383
        const int k = g >> 11, kc = (g >> 10) & 1, nt = (g >> 6) & 15, wl = g & 63;
        const int n = nt * 16 + (wl & 15);       // j row (fc1 output channel)
        const int ch0 = 24 + k * 64 + kc * 32 + (wl >> 4) * 8;
        float acc[8] = {0.f,0.f,0.f,0.f,0.f,0.f,0.f,0.f};
        for (int o = 0; o < 256; ++o) {
            const float f = ldin(fc1_w, n * 256 + o, f32);
            #pragma unroll
            for (int jj = 0; jj < 8; ++jj)
                acc[jj] = fmaf(f, ldin(pw1_w, o * 539 + ch0 + jj, f32), acc[jj]);
        }
        bf16 v[8];
        #pragma unroll
        for (int jj = 0; jj < 8; ++jj)
            v[jj] = f2b(acc[jj] * ldin(dw1_w, ch0 + jj, f32));
        *(short8x*)&WqP[(size_t)g * 8] = *(short8x*)v;
        return;
    }

    // ---- fold duty: B1 + ACO for output channel o = b ----
    __shared__ float row[539];
    __shared__ float red[256];
    const int o = b;

    for (int ch = tid; ch < 539; ch += 256) row[ch] = ldin(pw1_w, o * 539 + ch, f32);
    __syncthreads();

    float s = 0.f;
    for (int ch = tid; ch < 539; ch += 256) s += row[ch] * ldin(dw1_b, ch, f32);
    red[tid] = s;
    __syncthreads();
    for (int st = 128; st > 0; st >>= 1) {
        if (tid < st) red[tid] += red[tid + st];
        __syncthreads();
    }

    if (tid == 0) {
        float bacc = ldin(pw1_b, o, f32) + red[0];
        #pragma unroll
        for (int ch = 536; ch < 539; ++ch)
            bacc += 2.0f * row[ch] * ldin(dw1_w, ch, f32);
        F[F_B1 + o] = bacc;

        float A[6] = {0.f, 0.f, 0.f, 0.f, 0.f, 0.f};
        #pragma unroll
        for (int k = 0; k < 8; ++k) {
            A[(k >> 2)]           += row[3*k + 0] * ldin(dw1_w, 3*k + 0, f32);
            A[2 + ((k >> 1) & 1)] += row[3*k + 1] * ldin(dw1_w, 3*k + 1, f32);
            A[4 + (k & 1)]        += row[3*k + 2] * ldin(dw1_w, 3*k + 2, f32);
        }
        #pragma unroll
        for (int i = 0; i < 6; ++i) F[F_ACO + i * 256 + o] = A[i];
    }

    if (b == 0) {             // ---- prep0 duty (runs alongside fold in block 0) ----
        if (tid == 0) I[I_FLAG] = f32;
        for (int r = tid; r < 768; r += 256) F[F_FC2W + r] = ldin(fc2_w, r, f32);
        if (tid < 3) F[F_FC2B + tid] = ldin(fc2_b, tid, f32);
        if (tid < 3) {
            const int j = tid;
            float sb = ldin(sc_pw_b, j, f32);
            for (int c = 0; c < 64; ++c) {
                const float pw = ldin(sc_pw_w, j * 64 + c, f32);
                F[F_SCW + j * 64 + c] = pw * ldin(sc_dw_w, c, f32);
                sb += pw * ldin(sc_dw_b, c, f32);
            }
            F[F_SCB + j] = sb;
        }
        if (tid < TO) axis_tables(tid, TO, TI, F + F_DT, I + I_IT, I + I_LT0, I + I_LT1, F + F_FT);
        if (tid < HO) axis_tables(tid, HO, HI, F + F_DH, I + I_IH, I + I_LH0, I + I_LH1, F + F_FH);
        if (tid < WO) axis_tables(tid, WO, WI, F + F_DW, I + I_IW, I + I_LW0, I + I_LW1, F + F_FW);
    }
}

// ---------------- kernel B: MFMA corner projections Q + shortcut sc + b2/A2 fold ----------------
// grid (301 x 4). pt<300: M=32 positions, 2 corners {2y,2y+1}, N=256, K=64.
// pt==300,y==0: fold b2 = fc1_b + fc1·b1eff and A2 = fc1·A (needs all fold blocks of k_setup done).
__global__ __launch_bounds__(256)
void k_corner(const void* __restrict__ feat,
              const void* __restrict__ fc1_w, const void* __restrict__ fc1_b,
              float* __restrict__ F, const int* __restrict__ I,
              const bf16* __restrict__ WqP, bf16* __restrict__ Q) {
    const int tid = threadIdx.x;
    const int pt = blockIdx.x, y = blockIdx.y;
    const int f32 = I[I_FLAG];

    if (pt == 300) {          // ---- b2/A2 fold duty ----
        if (y != 0) return;
        const int j = tid;
        float accB = ldin(fc1_b, j, f32);
        float accA[6] = {0.f,0.f,0.f,0.f,0.f,0.f};
        for (int o = 0; o < 256; ++o) {
            const float f = ldin(fc1_w, j * 256 + o, f32);
            accB = fmaf(f, F[F_B1 + o], accB);
            #pragma unroll
            for (int i = 0; i < 6; ++i) accA[i] = fmaf(f, F[F_ACO + i * 256 + o], accA[i]);
        }
        F[F_B2 + j] = accB;
        #pragma unroll
        for (int i = 0; i < 6; ++i) F[F_A2 + i * 256 + j] = accA[i];
        return;
    }

    const int pos0 = pt * 32;
    __shared__ __align__(16) short ft[32 * FT_S];   // feat tile transposed [p][c] bf16
    __shared__ __align__(16) short zt[32 * ZPAD];   // Q tile [p][j] bf16

    // stage feat tile once for both corners (transpose [c][pos] -> [p][c])
    {
        const int p = tid & 31, c0 = tid >> 5;   // c0 in 0..7
        #pragma unroll
        for (int cc = 0; cc < 8; ++cc) {
            const int c = c0 * 8 + cc;
            ft[p * FT_S + c] = bbits(ldin(feat, c * NIN + pos0 + p, f32));
        }
    }
    __syncthreads();

    const int wl = tid & 63, w = tid >> 6;
    const int col = wl & 15, quad = wl >> 4;
    const short8x* bp = (const short8x*)WqP;

    #pragma unroll
    for (int c2 = 0; c2 < 2; ++c2) {
        const int k = y * 2 + c2;
        f32x4 acc[2][4] = { { {0,0,0,0},{0,0,0,0},{0,0,0,0},{0,0,0,0} },
                            { {0,0,0,0},{0,0,0,0},{0,0,0,0},{0,0,0,0} } };
        #pragma unroll
        for (int kc = 0; kc < 2; ++kc) {
            const short8x a0 = *(const short8x*)&ft[col * FT_S + kc * 32 + quad * 8];
            const short8x a1 = *(const short8x*)&ft[(col + 16) * FT_S + kc * 32 + quad * 8];
            #pragma unroll
            for (int nt = 0; nt < 4; ++nt) {
                const short8x bb = bp[((k * 2 + kc) * 16 + (w * 4 + nt)) * 64 + wl];
                acc[0][nt] = __builtin_amdgcn_mfma_f32_16x16x32_bf16(a0, bb, acc[0][nt], 0, 0, 0);
                acc[1][nt] = __builtin_amdgcn_mfma_f32_16x16x32_bf16(a1, bb, acc[1][nt], 0, 0, 0);
            }
        }

        // shortcut (once, on the y==0 blocks): sc[j][pos] from the staged tile
        if (c2 == 0 && y == 0 && tid < 96) {
            const int j = tid >> 5, p = tid & 31;
            float s = F[F_SCB + j];
            for (int c = 0; c < 64; ++c)
                s += bu2f((unsigned short)ft[p * FT_S + c]) * F[F_SCW + j * 64 + c];
            F[F_SC + j * NIN + pos0 + p] = s;
        }

        // write accumulators to LDS tile (D layout: m=quad*4+r, n=w*64+nt*16+col)
        #pragma unroll
        for (int mt = 0; mt < 2; ++mt)
            #pragma unroll
            for (int nt = 0; nt < 4; ++nt) {
                const int n = w * 64 + nt * 16 + col;
                #pragma unroll
                for (int r = 0; r < 4; ++r)
                    zt[(mt * 16 + quad * 4 + r) * ZPAD + n] = bbits(acc[mt][nt][r]);
            }
        __syncthreads();

        // coalesced store: 32 rows x 512B contiguous per row
        #pragma unroll
        for (int q = 0; q < 4; ++q) {
            const int i = q * 256 + tid;            // 0..1023 chunks of 8 bf16
            const int p = i >> 5, c8 = i & 31;
            const short8x v = *(const short8x*)&zt[p * ZPAD + c8 * 8];
            *(short8x*)(Q + ((size_t)(k * NIN + pos0 + p)) * 256 + c8 * 8) = v;
        }
        __syncthreads();   // zt reuse fence for next corner
    }
}

// ---------------- kernel C: main fused gather->gelu->fc2 (fc1 pre-folded into Q) ----------------
__global__ __launch_bounds__(256, 4)
void k_main(const bf16* __restrict__ Q, const float* __restrict__ F,
            const int* __restrict__ I, void* __restrict__ outv) {
    const int tid = threadIdx.x;
    const int pos0 = blockIdx.x * MPOS;
    const int f32 = I[I_FLAG];

    __shared__ int   sh_ipos[MPOS][8];
    __shared__ float sh_wk[MPOS][8];
    __shared__ float sh_dv[MPOS][6];
    __shared__ float sh_g[3][MPOS];
    __shared__ float redc[4][4][8][3];   // [wave][16-lane grp][pp][jj]

    // preload per-thread j-slice coefficients (independent of stage 1 -> issue before barrier)
    const int og = tid & 63, pg = tid >> 6;
    const int j4 = og * 4;
    const float4 b2v = *(const float4*)&F[F_B2 + j4];
    float4 A2v[6];
    #pragma unroll
    for (int i = 0; i < 6; ++i) A2v[i] = *(const float4*)&F[F_A2 + i * 256 + j4];
    const float4 fw0 = *(const float4*)&F[F_FC2W + j4];
    const float4 fw1 = *(const float4*)&F[F_FC2W + 256 + j4];
    const float4 fw2 = *(const float4*)&F[F_FC2W + 512 + j4];

    // ---- stage 1: per-position scalars (threads 0..31) ----
    if (tid < MPOS) {
        const int p = tid;
        const int pos = pos0 + p;
        const int t = pos / (HO * WO);
        const int rem = pos - t * (HO * WO);
        const int h = rem / WO;
        const int w = rem - h * WO;
        const int   iTa[2] = { I[I_IT + t], I[I_IT + TO + t] };
        const float dTv[2] = { F[F_DT + t], F[F_DT + TO + t] };
        const int   iHa[2] = { I[I_IH + h], I[I_IH + HO + h] };
        const float dHv[2] = { F[F_DH + h], F[F_DH + HO + h] };
        const int   iWa[2] = { I[I_IW + w], I[I_IW + WO + w] };
        const float dWv[2] = { F[F_DW + w], F[F_DW + WO + w] };
        sh_dv[p][0] = dTv[0]; sh_dv[p][1] = dTv[1];
        sh_dv[p][2] = dHv[0]; sh_dv[p][3] = dHv[1];
        sh_dv[p][4] = dWv[0]; sh_dv[p][5] = dWv[1];
        const float aT[2] = { fabsf(dTv[0]), fabsf(dTv[1]) };
        const float aH[2] = { fabsf(dHv[0]), fabsf(dHv[1]) };
        const float aW[2] = { fabsf(dWv[0]), fabsf(dWv[1]) };
        const float tot = (aT[0] + aT[1]) * (aH[0] + aH[1]) * (aW[0] + aW[1]) + 8e-9f;
        #pragma unroll
        for (int k = 0; k < 8; ++k) {
            const int at = k >> 2, ah = (k >> 1) & 1, aw = k & 1;
            sh_wk[p][k] = (aT[1 - at] * aH[1 - ah] * aW[1 - aw] + 1e-9f) / tot;
            sh_ipos[p][k] = iTa[at] * (HI * WI) + iHa[ah] * WI + iWa[aw];
        }
        // trilinear shortcut g
        const int a0 = I[I_LT0 + t], a1 = I[I_LT1 + t];
        const int bh0 = I[I_LH0 + h], bh1 = I[I_LH1 + h];
        const int c0 = I[I_LW0 + w], c1 = I[I_LW1 + w];
        const float fT = F[F_FT + t], fH = F[F_FH + h], fW = F[F_FW + w];
        #pragma unroll
        for (int jj = 0; jj < 3; ++jj) {
            const float* Sj = F + F_SC + jj * NIN;
            const int i0 = a0 * (HI * WI), i1 = a1 * (HI * WI);
            const float v000 = Sj[i0 + bh0 * WI + c0], v001 = Sj[i0 + bh0 * WI + c1];
            const float v010 = Sj[i0 + bh1 * WI + c0], v011 = Sj[i0 + bh1 * WI + c1];
            const float v100 = Sj[i1 + bh0 * WI + c0], v101 = Sj[i1 + bh0 * WI + c1];
            const float v110 = Sj[i1 + bh1 * WI + c0], v111 = Sj[i1 + bh1 * WI + c1];
            const float u00 = v000 * (1.f - fT) + v100 * fT;
            const float u01 = v001 * (1.f - fT) + v101 * fT;
            const float u10 = v010 * (1.f - fT) + v110 * fT;
            const float u11 = v011 * (1.f - fT) + v111 * fT;
            const float q0 = u00 * (1.f - fH) + u10 * fH;
            const float q1 = u01 * (1.f - fH) + u11 * fH;
            sh_g[jj][p] = q0 * (1.f - fW) + q1 * fW;
        }
    }
    __syncthreads();

    // ---- stage 2: fc1pre[p][j] = b2 + A2·dv + sum_k wk * Q[k][ipos][j]; gelu; fc2 partials ----
    // thread = (og, pg): 4 consecutive j channels j4=og*4, 8 positions p=pg*8+pp
    #pragma unroll
    for (int pp = 0; pp < 8; ++pp) {
        const int p = pg * 8 + pp;
        float a0 = b2v.x, a1 = b2v.y, a2 = b2v.z, a3 = b2v.w;
        #pragma unroll
        for (int i = 0; i < 6; ++i) {
            const float dv = sh_dv[p][i];
            a0 = fmaf(A2v[i].x, dv, a0); a1 = fmaf(A2v[i].y, dv, a1);
            a2 = fmaf(A2v[i].z, dv, a2); a3 = fmaf(A2v[i].w, dv, a3);
        }
        #pragma unroll
        for (int k = 0; k < 8; ++k) {
            const float wk = sh_wk[p][k];
            const ushort4x u = *(const ushort4x*)(Q + ((size_t)(k * NIN + sh_ipos[p][k])) * 256 + j4);
            a0 = fmaf(wk, bu2f(u.x), a0); a1 = fmaf(wk, bu2f(u.y), a1);
            a2 = fmaf(wk, bu2f(u.z), a2); a3 = fmaf(wk, bu2f(u.w), a3);
        }
        const float h0 = gelu_f(a0), h1 = gelu_f(a1), h2 = gelu_f(a2), h3 = gelu_f(a3);
        float pj0 = h0 * fw0.x; pj0 = fmaf(h1, fw0.y, pj0); pj0 = fmaf(h2, fw0.z, pj0); pj0 = fmaf(h3, fw0.w, pj0);
        float pj1 = h0 * fw1.x; pj1 = fmaf(h1, fw1.y, pj1); pj1 = fmaf(h2, fw1.z, pj1); pj1 = fmaf(h3, fw1.w, pj1);
        float pj2 = h0 * fw2.x; pj2 = fmaf(h1, fw2.y, pj2); pj2 = fmaf(h2, fw2.z, pj2); pj2 = fmaf(h3, fw2.w, pj2);
        // reduce over the 16 lanes of each j-group (j covers 64 channels per group)
        #pragma unroll
        for (int m = 1; m <= 8; m <<= 1) {
            pj0 += __shfl_xor(pj0, m, 64);
            pj1 += __shfl_xor(pj1, m, 64);
            pj2 += __shfl_xor(pj2, m, 64);
        }
        if ((og & 15) == 0) {
            const int grp = og >> 4;
            redc[pg][grp][pp][0] = pj0;
            redc[pg][grp][pp][1] = pj1;
            redc[pg][grp][pp][2] = pj2;
        }
    }
    __syncthreads();

    // ---- stage 3: combine 4 group-partials + shortcut + store ----
    if (tid < 96) {
        const int p = tid / 3, jj = tid - 3 * p;
        float a = F[F_FC2B + jj] + sh_g[jj][p];
        #pragma unroll
        for (int g4 = 0; g4 < 4; ++g4) a += redc[p >> 3][g4][p & 7][jj];
        const int oidx = jj * NOUT + pos0 + p;
        if (f32) ((float*)outv)[oidx] = a;
        else     ((bf16*)outv)[oidx] = f2b(a);
    }
}

extern "C" void kernel_launch(void* const* d_in, const int* in_sizes, int n_in,
                              void* d_out, int out_size, void* d_ws, size_t ws_size,
                              hipStream_t stream) {
    const void* feat    = d_in[0];
    const void* dw1_w   = d_in[1];
    const void* dw1_b   = d_in[2];
    const void* pw1_w   = d_in[3];
    const void* pw1_b   = d_in[4];
    const void* fc1_w   = d_in[5];
    const void* fc1_b   = d_in[6];
    const void* fc2_w   = d_in[7];
    const void* fc2_b   = d_in[8];
    const void* sc_dw_w = d_in[9];
    const void* sc_dw_b = d_in[10];
    const void* sc_pw_w = d_in[11];
    const void* sc_pw_b = d_in[12];

    const size_t Q_BYTES   = (size_t)8 * NIN * 256 * 2;   // 39,321,600
    const size_t WQP_BYTES = (size_t)16384 * 8 * 2;       // 262,144
    bf16*  Q    = (bf16*)d_ws;
    bf16*  WqP  = (bf16*)((char*)d_ws + Q_BYTES);
    float* F    = (float*)((char*)d_ws + Q_BYTES + WQP_BYTES);
    int*   I    = (int*)(F + F_END);
    // total ws need ~39.7 MB

    k_setup<<<320, 256, 0, stream>>>(feat, dw1_w, dw1_b, pw1_w, pw1_b, fc1_w, fc1_b,
                                     fc2_w, fc2_b, sc_dw_w, sc_dw_b, sc_pw_w, sc_pw_b,
                                     WqP, F, I);
    k_corner<<<dim3(301, 4), 256, 0, stream>>>(feat, fc1_w, fc1_b, F, I, WqP, Q);
    k_main<<<NOUT / MPOS, 256, 0, stream>>>(Q, F, I, (void*)d_out);
}

// Round 6
// 211.299 us; speedup vs baseline: 1.2760x; 1.2760x over previous
//
#include <hip/hip_runtime.h>
#include <hip/hip_bf16.h>

using bf16 = __hip_bfloat16;
typedef __attribute__((ext_vector_type(8))) short short8x;            // 8 bf16 (4 VGPRs)
typedef __attribute__((ext_vector_type(4))) short short4x;            // 4 bf16
typedef __attribute__((ext_vector_type(4))) unsigned short ushort4x;  // 4 bf16 bits
typedef __attribute__((ext_vector_type(4))) float f32x4;              // MFMA accumulator

__device__ __forceinline__ float b2f(bf16 x) { return __bfloat162float(x); }
__device__ __forceinline__ bf16  f2b(float x) { return __float2bfloat16(x); }
__device__ __forceinline__ short bbits(float x) { bf16 b = f2b(x); short s; __builtin_memcpy(&s, &b, 2); return s; }
__device__ __forceinline__ float bu2f(unsigned short s) {
    unsigned v = ((unsigned)s) << 16; float f; __builtin_memcpy(&f, &v, 4); return f;
}
// flag-dispatched input load: f32==1 -> fp32 storage, else bf16 storage
__device__ __forceinline__ float ldin(const void* p, int i, int f32) {
    return f32 ? ((const float*)p)[i] : b2f(((const bf16*)p)[i]);
}

// branchless erf-based gelu (A&S 7.1.26, |eps_erf| <= 1.5e-7) — replaces libm erff
__device__ __forceinline__ float gelu_f(float x) {
    const float u = x * 0.70710678118654752f;
    const float z = fabsf(u);
    const float t = __builtin_amdgcn_rcpf(fmaf(0.3275911f, z, 1.0f));
    float pl = fmaf(1.061405429f, t, -1.453152027f);
    pl = fmaf(pl, t, 1.421413741f);
    pl = fmaf(pl, t, -0.284496736f);
    pl = fmaf(pl, t, 0.254829592f);
    pl *= t;
    const float e = __builtin_amdgcn_exp2f((z * z) * -1.4426950408889634f);
    float er = fmaf(-pl, e, 1.0f);          // erf(|u|)
    er = __builtin_copysignf(er, u);        // erf(u)
    const float g = 0.5f * x;
    return fmaf(g, er, g);                  // 0.5*x*(1+erf)
}

// problem dims (fixed by setup_inputs)
#define TI 6
#define HI 40
#define WI 40
#define TO 12
#define HO 80
#define WO 80
#define NIN (TI*HI*WI)    // 9600
#define NOUT (TO*HO*WO)   // 76800

// ---------------- workspace layout ----------------
// [0, Q_BYTES)            : Q bf16 [8][NIN][256]  (corner projections through fc1: Q=feat·Wq^T)
// [+WQP_BYTES)            : WqP bf16 [8 k][2 kc][16 nt][64 lane][8]  (Wq B-fragments)
// float region F (offsets in floats):
#define F_B1    0                       // [256] effective pw1 bias (o-space)
#define F_ACO   (F_B1 + 256)            // [6][256] rel-coord coefficients (o-space)
#define F_SCW   (F_ACO + 6*256)         // [3][64] sc_pw_w*sc_dw_w
#define F_SCB   (F_SCW + 3*64)          // [3] folded sc bias (pad 4)
#define F_SC    (F_SCB + 4)             // [3][NIN] shortcut conv output
#define F_DT    (F_SC + 3*NIN)          // [2][TO] signed d (t axis)
#define F_DH    (F_DT + 2*TO)           // [2][HO]
#define F_DW    (F_DH + 2*HO)           // [2][WO]
#define F_FT    (F_DW + 2*WO)           // [TO] trilinear frac
#define F_FH    (F_FT + TO)             // [HO]
#define F_FW    (F_FH + HO)             // [WO]
#define F_FC2W  (F_FW + WO)             // [3*256] fc2 weights (fp32 staged)
#define F_FC2B  (F_FC2W + 768)          // [3] fc2 bias (pad 4)
#define F_B2    (F_FC2B + 4)            // [256] fc1-folded bias: fc1_b + fc1_w·b1eff
#define F_A2    (F_B2 + 256)            // [6][256] fc1-folded coord coeffs: fc1_w·A
#define F_END   (F_A2 + 6*256)
// int region I (offsets in ints), starts right after F region:
#define I_IT    0                       // [2][TO] nearest idx
#define I_IH    (I_IT + 2*TO)           // [2][HO]
#define I_IW    (I_IH + 2*HO)           // [2][WO]
#define I_LT0   (I_IW + 2*WO)           // [TO] trilinear i0
#define I_LT1   (I_LT0 + TO)
#define I_LH0   (I_LT1 + TO)
#define I_LH1   (I_LH0 + HO)
#define I_LW0   (I_LH1 + HO)
#define I_LW1   (I_LW0 + WO)
#define I_FLAG  (I_LW1 + WO)            // [1] 1 = fp32 storage, 0 = bf16 storage
#define I_END   (I_FLAG + 1)

#define MPOS 32     // positions per k_main block
#define ZPAD 264    // bf16 row stride for zt LDS tile in k_corner
#define FT_S 72     // bf16 row stride for feat tile in k_corner (16B-aligned rows)
#define WQS 68      // fp32 row stride for Wq-fold LDS tiles (16B-aligned, conflict-mild)

// per-axis tables, replicating reference `near` (eps=1e-6, round-half-even) and `lin_idx`
__device__ __forceinline__ void axis_tables(int i, int n_out, int n_in,
                                            float* dvals, int* ivals,
                                            int* l0, int* l1, float* fr) {
    const float r_out = 1.0f / (float)n_out;
    const float r_in  = 1.0f / (float)n_in;
    const float c = -1.0f + r_out + 2.0f * r_out * (float)i;
    #pragma unroll
    for (int v = 0; v < 2; ++v) {
        const float vv = v ? 1.0f : -1.0f;
        float cc = c + vv * r_in + 1e-6f;
        cc = fminf(fmaxf(cc, -1.0f + 1e-6f), 1.0f - 1e-6f);
        float fx = rintf(((cc + 1.0f) * (float)n_in - 1.0f) * 0.5f);
        fx = fminf(fmaxf(fx, 0.0f), (float)(n_in - 1));
        const int idx = (int)fx;
        const float l = -1.0f + r_in + 2.0f * r_in * (float)idx;
        dvals[v * n_out + i] = (c - l) * (float)n_in;
        ivals[v * n_out + i] = idx;
    }
    float x = fminf(fmaxf(((c + 1.0f) * (float)n_in - 1.0f) * 0.5f, 0.0f), (float)(n_in - 1));
    const float x0 = floorf(x);
    fr[i] = x - x0;
    const int i0 = (int)x0;
    l0[i] = i0;
    l1[i] = min(i0 + 1, n_in - 1);
}

// ---------------- kernel A: merged setup (288 blocks) ----------------
// blocks 0..255 : B1/ACO fold per output channel o (block 0 also: tables + small folds)
// blocks 256..287: LDS-tiled fp32 GEMM Wq = fc1_w · (pw1_w·dw1_w feature cols) -> B-fragments
//                  32 blocks x (64j x 64ch) tile, K=256 in chunks of 32.
__global__ __launch_bounds__(256)
void k_setup(const void* __restrict__ feat,
             const void* __restrict__ dw1_w, const void* __restrict__ dw1_b,
             const void* __restrict__ pw1_w, const void* __restrict__ pw1_b,
             const void* __restrict__ fc1_w, const void* __restrict__ fc1_b,
             const void* __restrict__ fc2_w, const void* __restrict__ fc2_b,
             const void* __restrict__ sc_dw_w, const void* __restrict__ sc_dw_b,
             const void* __restrict__ sc_pw_w, const void* __restrict__ sc_pw_b,
             bf16* __restrict__ WqP, float* __restrict__ F, int* __restrict__ I) {
    const int tid = threadIdx.x;
    const int b = blockIdx.x;
    __shared__ int sflag;
    __shared__ __align__(16) float smem[2 * 32 * WQS];   // 17408 B, reused by both duties
    // per-block dtype detection (wave-0 ballot): even halfwords of fp32 data
    // are mantissa junk (~15% in bf16-exponent window); of bf16 data ~100%.
    if (tid < 64) {
        const unsigned short* u = (const unsigned short*)feat;
        const unsigned e = (u[2 * tid] >> 7) & 0xFFu;
        const unsigned long long m = __ballot(e >= 0x68u && e <= 0x8Eu);
        if (tid == 0) sflag = (__popcll(m) < 32) ? 1 : 0;
    }
    __syncthreads();
    const int f32 = sflag;

    if (b >= 256) {           // ---- Wq fold duty: tiled GEMM, coalesced staging ----
        const int pb = b - 256;                  // 0..31
        const int j0 = (pb & 3) * 64;            // j tile base
        const int c0g = (pb >> 2) * 64;          // ch tile base (c' in 0..511)
        float* fcsT = smem;                      // [32 o][64 j] stride WQS (transposed fc1 chunk)
        float* pws  = smem + 32 * WQS;           // [32 o][64 ch] stride WQS
        const int tj = tid & 15, tc = tid >> 4;  // thread 4x4 register tile
        float acc[4][4] = { {0,0,0,0},{0,0,0,0},{0,0,0,0},{0,0,0,0} };

        for (int oc = 0; oc < 8; ++oc) {
            const int o0 = oc * 32;
            #pragma unroll
            for (int r = 0; r < 8; ++r) {        // fc1_w [64j x 32o] -> fcsT[o][j]
                const int idx = r * 256 + tid;
                const int o = idx & 31, jl = idx >> 5;
                fcsT[o * WQS + jl] = ldin(fc1_w, (j0 + jl) * 256 + o0 + o, f32);
            }
            #pragma unroll
            for (int r = 0; r < 8; ++r) {        // pw1_w [32o x 64ch] -> pws[o][ch]
                const int idx = r * 256 + tid;
                const int ch = idx & 63, o = idx >> 6;
                pws[o * WQS + ch] = ldin(pw1_w, (o0 + o) * 539 + 24 + c0g + ch, f32);
            }
            __syncthreads();
            #pragma unroll
            for (int o = 0; o < 32; ++o) {
                const float4 av = *(const float4*)&fcsT[o * WQS + tj * 4];
                const float4 bv = *(const float4*)&pws[o * WQS + tc * 4];
                const float a4[4] = { av.x, av.y, av.z, av.w };
                const float b4[4] = { bv.x, bv.y, bv.z, bv.w };
                #pragma unroll
                for (int ji = 0; ji < 4; ++ji)
                    #pragma unroll
                    for (int ci = 0; ci < 4; ++ci)
                        acc[ji][ci] = fmaf(a4[ji], b4[ci], acc[ji][ci]);
            }
            __syncthreads();
        }

        // epilogue: scale by dw1_w, convert, store in MFMA B-fragment layout
        float dsc[4];
        #pragma unroll
        for (int ci = 0; ci < 4; ++ci) dsc[ci] = ldin(dw1_w, 24 + c0g + tc * 4 + ci, f32);
        const int cp0 = c0g + tc * 4;            // c' of ci=0 (multiple of 4)
        const int k2 = cp0 >> 5, e = (cp0 >> 3) & 3, jj0 = cp0 & 7;
        #pragma unroll
        for (int ji = 0; ji < 4; ++ji) {
            const int j = j0 + tj * 4 + ji;
            const int nt = j >> 4, wlo = j & 15;
            const size_t flat = ((((size_t)(k2 * 16 + nt) * 4 + e) * 16 + wlo) * 8 + jj0);
            short v[4];
            #pragma unroll
            for (int ci = 0; ci < 4; ++ci) v[ci] = bbits(acc[ji][ci] * dsc[ci]);
            *(short4x*)&WqP[flat] = *(short4x*)v;
        }
        return;
    }

    // ---- fold duty: B1 + ACO for output channel o = b ----
    float* row = smem;          // [539]
    float* red = smem + 544;    // [256]
    const int o = b;

    for (int ch = tid; ch < 539; ch += 256) row[ch] = ldin(pw1_w, o * 539 + ch, f32);
    __syncthreads();

    float s = 0.f;
    for (int ch = tid; ch < 539; ch += 256) s += row[ch] * ldin(dw1_b, ch, f32);
    red[tid] = s;
    __syncthreads();
    for (int st = 128; st > 0; st >>= 1) {
        if (tid < st) red[tid] += red[tid + st];
        __syncthreads();
    }

    if (tid == 0) {
        float bacc = ldin(pw1_b, o, f32) + red[0];
        #pragma unroll
        for (int ch = 536; ch < 539; ++ch)
            bacc += 2.0f * row[ch] * ldin(dw1_w, ch, f32);
        F[F_B1 + o] = bacc;

        float A[6] = {0.f, 0.f, 0.f, 0.f, 0.f, 0.f};
        #pragma unroll
        for (int k = 0; k < 8; ++k) {
            A[(k >> 2)]           += row[3*k + 0] * ldin(dw1_w, 3*k + 0, f32);
            A[2 + ((k >> 1) & 1)] += row[3*k + 1] * ldin(dw1_w, 3*k + 1, f32);
            A[4 + (k & 1)]        += row[3*k + 2] * ldin(dw1_w, 3*k + 2, f32);
        }
        #pragma unroll
        for (int i = 0; i < 6; ++i) F[F_ACO + i * 256 + o] = A[i];
    }

    if (b == 0) {             // ---- prep0 duty (runs alongside fold in block 0) ----
        if (tid == 0) I[I_FLAG] = f32;
        for (int r = tid; r < 768; r += 256) F[F_FC2W + r] = ldin(fc2_w, r, f32);
        if (tid < 3) F[F_FC2B + tid] = ldin(fc2_b, tid, f32);
        if (tid < 3) {
            const int j = tid;
            float sb = ldin(sc_pw_b, j, f32);
            for (int c = 0; c < 64; ++c) {
                const float pw = ldin(sc_pw_w, j * 64 + c, f32);
                F[F_SCW + j * 64 + c] = pw * ldin(sc_dw_w, c, f32);
                sb += pw * ldin(sc_dw_b, c, f32);
            }
            F[F_SCB + j] = sb;
        }
        if (tid < TO) axis_tables(tid, TO, TI, F + F_DT, I + I_IT, I + I_LT0, I + I_LT1, F + F_FT);
        if (tid < HO) axis_tables(tid, HO, HI, F + F_DH, I + I_IH, I + I_LH0, I + I_LH1, F + F_FH);
        if (tid < WO) axis_tables(tid, WO, WI, F + F_DW, I + I_IW, I + I_LW0, I + I_LW1, F + F_FW);
    }
}

// ---------------- kernel B: MFMA corner projections Q + shortcut sc + b2/A2 fold ----------------
// grid (301 x 4). pt<300: M=32 positions, 2 corners {2y,2y+1}, N=256, K=64.
// pt==300,y==0: fold b2 = fc1_b + fc1·b1eff and A2 = fc1·A (needs all fold blocks of k_setup done).
__global__ __launch_bounds__(256)
void k_corner(const void* __restrict__ feat,
              const void* __restrict__ fc1_w, const void* __restrict__ fc1_b,
              float* __restrict__ F, const int* __restrict__ I,
              const bf16* __restrict__ WqP, bf16* __restrict__ Q) {
    const int tid = threadIdx.x;
    const int pt = blockIdx.x, y = blockIdx.y;
    const int f32 = I[I_FLAG];

    if (pt == 300) {          // ---- b2/A2 fold duty ----
        if (y != 0) return;
        const int j = tid;
        float accB = ldin(fc1_b, j, f32);
        float accA[6] = {0.f,0.f,0.f,0.f,0.f,0.f};
        for (int o = 0; o < 256; ++o) {
            const float f = ldin(fc1_w, j * 256 + o, f32);
            accB = fmaf(f, F[F_B1 + o], accB);
            #pragma unroll
            for (int i = 0; i < 6; ++i) accA[i] = fmaf(f, F[F_ACO + i * 256 + o], accA[i]);
        }
        F[F_B2 + j] = accB;
        #pragma unroll
        for (int i = 0; i < 6; ++i) F[F_A2 + i * 256 + j] = accA[i];
        return;
    }

    const int pos0 = pt * 32;
    __shared__ __align__(16) short ft[32 * FT_S];   // feat tile transposed [p][c] bf16
    __shared__ __align__(16) short zt[32 * ZPAD];   // Q tile [p][j] bf16

    // stage feat tile once for both corners (transpose [c][pos] -> [p][c])
    {
        const int p = tid & 31, c0 = tid >> 5;   // c0 in 0..7
        #pragma unroll
        for (int cc = 0; cc < 8; ++cc) {
            const int c = c0 * 8 + cc;
            ft[p * FT_S + c] = bbits(ldin(feat, c * NIN + pos0 + p, f32));
        }
    }
    __syncthreads();

    const int wl = tid & 63, w = tid >> 6;
    const int col = wl & 15, quad = wl >> 4;
    const short8x* bp = (const short8x*)WqP;

    #pragma unroll
    for (int c2 = 0; c2 < 2; ++c2) {
        const int k = y * 2 + c2;
        f32x4 acc[2][4] = { { {0,0,0,0},{0,0,0,0},{0,0,0,0},{0,0,0,0} },
                            { {0,0,0,0},{0,0,0,0},{0,0,0,0},{0,0,0,0} } };
        #pragma unroll
        for (int kc = 0; kc < 2; ++kc) {
            const short8x a0 = *(const short8x*)&ft[col * FT_S + kc * 32 + quad * 8];
            const short8x a1 = *(const short8x*)&ft[(col + 16) * FT_S + kc * 32 + quad * 8];
            #pragma unroll
            for (int nt = 0; nt < 4; ++nt) {
                const short8x bb = bp[((k * 2 + kc) * 16 + (w * 4 + nt)) * 64 + wl];
                acc[0][nt] = __builtin_amdgcn_mfma_f32_16x16x32_bf16(a0, bb, acc[0][nt], 0, 0, 0);
                acc[1][nt] = __builtin_amdgcn_mfma_f32_16x16x32_bf16(a1, bb, acc[1][nt], 0, 0, 0);
            }
        }

        // shortcut (once, on the y==0 blocks): sc[j][pos] from the staged tile
        if (c2 == 0 && y == 0 && tid < 96) {
            const int j = tid >> 5, p = tid & 31;
            float s = F[F_SCB + j];
            for (int c = 0; c < 64; ++c)
                s += bu2f((unsigned short)ft[p * FT_S + c]) * F[F_SCW + j * 64 + c];
            F[F_SC + j * NIN + pos0 + p] = s;
        }

        // write accumulators to LDS tile (D layout: m=quad*4+r, n=w*64+nt*16+col)
        #pragma unroll
        for (int mt = 0; mt < 2; ++mt)
            #pragma unroll
            for (int nt = 0; nt < 4; ++nt) {
                const int n = w * 64 + nt * 16 + col;
                #pragma unroll
                for (int r = 0; r < 4; ++r)
                    zt[(mt * 16 + quad * 4 + r) * ZPAD + n] = bbits(acc[mt][nt][r]);
            }
        __syncthreads();

        // coalesced store: 32 rows x 512B contiguous per row
        #pragma unroll
        for (int q = 0; q < 4; ++q) {
            const int i = q * 256 + tid;            // 0..1023 chunks of 8 bf16
            const int p = i >> 5, c8 = i & 31;
            const short8x v = *(const short8x*)&zt[p * ZPAD + c8 * 8];
            *(short8x*)(Q + ((size_t)(k * NIN + pos0 + p)) * 256 + c8 * 8) = v;
        }
        __syncthreads();   // zt reuse fence for next corner
    }
}

// ---------------- kernel C: main fused gather->gelu->fc2 (fc1 pre-folded into Q) ----------------
__global__ __launch_bounds__(256, 4)
void k_main(const bf16* __restrict__ Q, const float* __restrict__ F,
            const int* __restrict__ I, void* __restrict__ outv) {
    const int tid = threadIdx.x;
    const int pos0 = blockIdx.x * MPOS;
    const int f32 = I[I_FLAG];

    __shared__ int   sh_ipos[MPOS][8];
    __shared__ float sh_wk[MPOS][8];
    __shared__ float sh_dv[MPOS][6];
    __shared__ float sh_g[3][MPOS];
    __shared__ float redc[4][4][8][3];   // [wave][16-lane grp][pp][jj]

    // preload per-thread j-slice coefficients (independent of stage 1 -> issue before barrier)
    const int og = tid & 63, pg = tid >> 6;
    const int j4 = og * 4;
    const float4 b2v = *(const float4*)&F[F_B2 + j4];
    float4 A2v[6];
    #pragma unroll
    for (int i = 0; i < 6; ++i) A2v[i] = *(const float4*)&F[F_A2 + i * 256 + j4];
    const float4 fw0 = *(const float4*)&F[F_FC2W + j4];
    const float4 fw1 = *(const float4*)&F[F_FC2W + 256 + j4];
    const float4 fw2 = *(const float4*)&F[F_FC2W + 512 + j4];

    // ---- stage 1: per-position scalars (threads 0..31) ----
    if (tid < MPOS) {
        const int p = tid;
        const int pos = pos0 + p;
        const int t = pos / (HO * WO);
        const int rem = pos - t * (HO * WO);
        const int h = rem / WO;
        const int w = rem - h * WO;
        const int   iTa[2] = { I[I_IT + t], I[I_IT + TO + t] };
        const float dTv[2] = { F[F_DT + t], F[F_DT + TO + t] };
        const int   iHa[2] = { I[I_IH + h], I[I_IH + HO + h] };
        const float dHv[2] = { F[F_DH + h], F[F_DH + HO + h] };
        const int   iWa[2] = { I[I_IW + w], I[I_IW + WO + w] };
        const float dWv[2] = { F[F_DW + w], F[F_DW + WO + w] };
        sh_dv[p][0] = dTv[0]; sh_dv[p][1] = dTv[1];
        sh_dv[p][2] = dHv[0]; sh_dv[p][3] = dHv[1];
        sh_dv[p][4] = dWv[0]; sh_dv[p][5] = dWv[1];
        const float aT[2] = { fabsf(dTv[0]), fabsf(dTv[1]) };
        const float aH[2] = { fabsf(dHv[0]), fabsf(dHv[1]) };
        const float aW[2] = { fabsf(dWv[0]), fabsf(dWv[1]) };
        const float tot = (aT[0] + aT[1]) * (aH[0] + aH[1]) * (aW[0] + aW[1]) + 8e-9f;
        #pragma unroll
        for (int k = 0; k < 8; ++k) {
            const int at = k >> 2, ah = (k >> 1) & 1, aw = k & 1;
            sh_wk[p][k] = (aT[1 - at] * aH[1 - ah] * aW[1 - aw] + 1e-9f) / tot;
            sh_ipos[p][k] = iTa[at] * (HI * WI) + iHa[ah] * WI + iWa[aw];
        }
        // trilinear shortcut g
        const int a0 = I[I_LT0 + t], a1 = I[I_LT1 + t];
        const int bh0 = I[I_LH0 + h], bh1 = I[I_LH1 + h];
        const int c0 = I[I_LW0 + w], c1 = I[I_LW1 + w];
        const float fT = F[F_FT + t], fH = F[F_FH + h], fW = F[F_FW + w];
        #pragma unroll
        for (int jj = 0; jj < 3; ++jj) {
            const float* Sj = F + F_SC + jj * NIN;
            const int i0 = a0 * (HI * WI), i1 = a1 * (HI * WI);
            const float v000 = Sj[i0 + bh0 * WI + c0], v001 = Sj[i0 + bh0 * WI + c1];
            const float v010 = Sj[i0 + bh1 * WI + c0], v011 = Sj[i0 + bh1 * WI + c1];
            const float v100 = Sj[i1 + bh0 * WI + c0], v101 = Sj[i1 + bh0 * WI + c1];
            const float v110 = Sj[i1 + bh1 * WI + c0], v111 = Sj[i1 + bh1 * WI + c1];
            const float u00 = v000 * (1.f - fT) + v100 * fT;
            const float u01 = v001 * (1.f - fT) + v101 * fT;
            const float u10 = v010 * (1.f - fT) + v110 * fT;
            const float u11 = v011 * (1.f - fT) + v111 * fT;
            const float q0 = u00 * (1.f - fH) + u10 * fH;
            const float q1 = u01 * (1.f - fH) + u11 * fH;
            sh_g[jj][p] = q0 * (1.f - fW) + q1 * fW;
        }
    }
    __syncthreads();

    // ---- stage 2: fc1pre[p][j] = b2 + A2·dv + sum_k wk * Q[k][ipos][j]; gelu; fc2 partials ----
    // thread = (og, pg): 4 consecutive j channels j4=og*4, 8 positions p=pg*8+pp
    #pragma unroll
    for (int pp = 0; pp < 8; ++pp) {
        const int p = pg * 8 + pp;
        float a0 = b2v.x, a1 = b2v.y, a2 = b2v.z, a3 = b2v.w;
        #pragma unroll
        for (int i = 0; i < 6; ++i) {
            const float dv = sh_dv[p][i];
            a0 = fmaf(A2v[i].x, dv, a0); a1 = fmaf(A2v[i].y, dv, a1);
            a2 = fmaf(A2v[i].z, dv, a2); a3 = fmaf(A2v[i].w, dv, a3);
        }
        #pragma unroll
        for (int k = 0; k < 8; ++k) {
            const float wk = sh_wk[p][k];
            const ushort4x u = *(const ushort4x*)(Q + ((size_t)(k * NIN + sh_ipos[p][k])) * 256 + j4);
            a0 = fmaf(wk, bu2f(u.x), a0); a1 = fmaf(wk, bu2f(u.y), a1);
            a2 = fmaf(wk, bu2f(u.z), a2); a3 = fmaf(wk, bu2f(u.w), a3);
        }
        const float h0 = gelu_f(a0), h1 = gelu_f(a1), h2 = gelu_f(a2), h3 = gelu_f(a3);
        float pj0 = h0 * fw0.x; pj0 = fmaf(h1, fw0.y, pj0); pj0 = fmaf(h2, fw0.z, pj0); pj0 = fmaf(h3, fw0.w, pj0);
        float pj1 = h0 * fw1.x; pj1 = fmaf(h1, fw1.y, pj1); pj1 = fmaf(h2, fw1.z, pj1); pj1 = fmaf(h3, fw1.w, pj1);
        float pj2 = h0 * fw2.x; pj2 = fmaf(h1, fw2.y, pj2); pj2 = fmaf(h2, fw2.z, pj2); pj2 = fmaf(h3, fw2.w, pj2);
        // reduce over the 16 lanes of each j-group (j covers 64 channels per group)
        #pragma unroll
        for (int m = 1; m <= 8; m <<= 1) {
            pj0 += __shfl_xor(pj0, m, 64);
            pj1 += __shfl_xor(pj1, m, 64);
            pj2 += __shfl_xor(pj2, m, 64);
        }
        if ((og & 15) == 0) {
            const int grp = og >> 4;
            redc[pg][grp][pp][0] = pj0;
            redc[pg][grp][pp][1] = pj1;
            redc[pg][grp][pp][2] = pj2;
        }
    }
    __syncthreads();

    // ---- stage 3: combine 4 group-partials + shortcut + store ----
    if (tid < 96) {
        const int p = tid / 3, jj = tid - 3 * p;
        float a = F[F_FC2B + jj] + sh_g[jj][p];
        #pragma unroll
        for (int g4 = 0; g4 < 4; ++g4) a += redc[p >> 3][g4][p & 7][jj];
        const int oidx = jj * NOUT + pos0 + p;
        if (f32) ((float*)outv)[oidx] = a;
        else     ((bf16*)outv)[oidx] = f2b(a);
    }
}

extern "C" void kernel_launch(void* const* d_in, const int* in_sizes, int n_in,
                              void* d_out, int out_size, void* d_ws, size_t ws_size,
                              hipStream_t stream) {
    const void* feat    = d_in[0];
    const void* dw1_w   = d_in[1];
    const void* dw1_b   = d_in[2];
    const void* pw1_w   = d_in[3];
    const void* pw1_b   = d_in[4];
    const void* fc1_w   = d_in[5];
    const void* fc1_b   = d_in[6];
    const void* fc2_w   = d_in[7];
    const void* fc2_b   = d_in[8];
    const void* sc_dw_w = d_in[9];
    const void* sc_dw_b = d_in[10];
    const void* sc_pw_w = d_in[11];
    const void* sc_pw_b = d_in[12];

    const size_t Q_BYTES   = (size_t)8 * NIN * 256 * 2;   // 39,321,600
    const size_t WQP_BYTES = (size_t)16384 * 8 * 2;       // 262,144
    bf16*  Q    = (bf16*)d_ws;
    bf16*  WqP  = (bf16*)((char*)d_ws + Q_BYTES);
    float* F    = (float*)((char*)d_ws + Q_BYTES + WQP_BYTES);
    int*   I    = (int*)(F + F_END);
    // total ws need ~39.7 MB

    k_setup<<<288, 256, 0, stream>>>(feat, dw1_w, dw1_b, pw1_w, pw1_b, fc1_w, fc1_b,
                                     fc2_w, fc2_b, sc_dw_w, sc_dw_b, sc_pw_w, sc_pw_b,
                                     WqP, F, I);
    k_corner<<<dim3(301, 4), 256, 0, stream>>>(feat, fc1_w, fc1_b, F, I, WqP, Q);
    k_main<<<NOUT / MPOS, 256, 0, stream>>>(Q, F, I, (void*)d_out);
}